// Round 4
// baseline (518.568 us; speedup 1.0000x reference)
//
#include <hip/hip_runtime.h>
#include <stdint.h>

typedef __bf16 bf16x8 __attribute__((ext_vector_type(8)));
typedef float f32x4 __attribute__((ext_vector_type(4)));

// ---------------------------------------------------------------------------
// Fused prep: (a) f32->bf16 convert of the 4 weight matrices, (b) time-shift
// mix producing all three mixed A-matrices (bf16). Block-uniform branch.
// ---------------------------------------------------------------------------
__global__ void prep_kernel(const float* __restrict__ w0, const float* __restrict__ w1,
                            const float* __restrict__ w2, const float* __restrict__ w3,
                            __bf16* __restrict__ o0, __bf16* __restrict__ o1,
                            __bf16* __restrict__ o2, __bf16* __restrict__ o3,
                            long DD, unsigned cvtBlocks,
                            const float* __restrict__ x,
                            const float* __restrict__ mk, const float* __restrict__ mv,
                            const float* __restrict__ mr,
                            __bf16* __restrict__ ok, __bf16* __restrict__ ov,
                            __bf16* __restrict__ orr,
                            int T, int D, long total) {
    if (blockIdx.x < cvtBlocks) {
        long idx = ((long)blockIdx.x * blockDim.x + threadIdx.x) * 8;
        if (idx >= 4 * DD) return;
        int w = (int)(idx / DD);            // block-uniform (DD % 2048 == 0)
        long off = idx - (long)w * DD;
        const float* in = (w == 0) ? w0 : (w == 1) ? w1 : (w == 2) ? w2 : w3;
        __bf16* out     = (w == 0) ? o0 : (w == 1) ? o1 : (w == 2) ? o2 : o3;
        f32x4 a = *(const f32x4*)(in + off);
        f32x4 b = *(const f32x4*)(in + off + 4);
        bf16x8 o;
#pragma unroll
        for (int i = 0; i < 4; ++i) { o[i] = (__bf16)a[i]; o[i + 4] = (__bf16)b[i]; }
        *(bf16x8*)(out + off) = o;
    } else {
        long idx = ((long)(blockIdx.x - cvtBlocks) * blockDim.x + threadIdx.x) * 8;
        if (idx >= total) return;
        int d = (int)(idx % D);
        long bt = idx / D;
        int t = (int)(bt % T);

        f32x4 x0 = *(const f32x4*)(x + idx);
        f32x4 x1 = *(const f32x4*)(x + idx + 4);
        f32x4 l0 = {}, l1 = {};
        if (t != 0) {
            l0 = *(const f32x4*)(x + idx - D);
            l1 = *(const f32x4*)(x + idx - D + 4);
        }
        const float* mw[3] = {mk, mv, mr};
        __bf16* ow[3] = {ok, ov, orr};
#pragma unroll
        for (int s = 0; s < 3; ++s) {
            f32x4 m0 = *(const f32x4*)(mw[s] + d);
            f32x4 m1 = *(const f32x4*)(mw[s] + d + 4);
            bf16x8 o;
#pragma unroll
            for (int i = 0; i < 4; ++i) {
                o[i]     = (__bf16)(x0[i] * m0[i] + l0[i] * (1.0f - m0[i]));
                o[i + 4] = (__bf16)(x1[i] * m1[i] + l1[i] * (1.0f - m1[i]));
            }
            *(bf16x8*)(ow[s] + idx) = o;
        }
    }
}

// ---------------------------------------------------------------------------
// 256x256 fine-interleaved pipelined GEMM (T1+T2+T3/T4+T5).
// 512 threads = 8 waves (2M x 4N); per-wave output 128x64.
// BK=32, THREE rotating LDS buffers (96 KiB total) -> tile t staged 2 tiles
// ahead, 2 global_load_lds per thread per phase; at each tile boundary
// s_waitcnt vmcnt(4) BEFORE the barrier (counted, never 0 in steady state):
// the barrier then certifies block-wide that every wave's 4 oldest loads
// (= next tile) have landed. Two phases/tile, each:
//   {ds_read 8|4} {stage 2} s_barrier lgkmcnt(0) setprio(1) 16xMFMA setprio(0)
// LDS swizzle: [256][32] bf16 rows, chunk(16B) index ^= (row>>1)&3;
// stage side writes linearly (global src pre-swizzled with the same XOR),
// read side applies the XOR -> each frag-read covers a contiguous 1KB
// exactly once across the 64 lanes (conflict-free).
// r4 fix: LDS is declared ONCE in each __global__ kernel and passed in --
// gemm3's two template instantiations (bf16/f32 out) were each carrying
// their own 96 KiB static __shared__ (196608 B > 163840 B limit).
// ---------------------------------------------------------------------------
template <typename CT>
__device__ __attribute__((always_inline))
void gemm_body(const __bf16* __restrict__ A, const __bf16* __restrict__ Bt,
               CT* __restrict__ C, int M, int N, int K,
               __bf16* sA, __bf16* sB) {
    const int tid  = threadIdx.x;
    const int lane = tid & 63;
    const int wave = tid >> 6;
    const int wm = wave >> 2;          // 0..1  (M half)
    const int wn = wave & 3;           // 0..3  (N quarter)

    // T1: XCD-aware bijective swizzle (nwg = 256 per z-slice, % 8 == 0)
    const int id  = blockIdx.y * gridDim.x + blockIdx.x;
    const int nwg = gridDim.x * gridDim.y;
    const int wg  = (id & 7) * (nwg >> 3) + (id >> 3);
    const int bx  = wg % gridDim.x;
    const int by  = wg / gridDim.x;
    const int m0 = by * 256;
    const int n0 = bx * 256;

    // staging addresses: thread -> (row = tid>>2 [+128 for round 1],
    // chunk = tid&3); global col pre-swizzled chunk ^ (row>>1)&3.
    const int srow = tid >> 2;
    const int scol = ((tid & 3) ^ ((tid >> 3) & 3)) << 3;
    const __bf16* gA0 = A  + (long)(m0 + srow) * K + scol;
    const __bf16* gB0 = Bt + (long)(n0 + srow) * K + scol;
    const int ldsoff = wave * 512;         // elems; +lane*8 applied by HW
    const long rstep = (long)128 * K;

    const int q  = lane >> 4;
    const int ml = lane & 15;
    const int coff = ((q ^ (ml >> 1)) & 3) << 3;   // swizzled k-chunk (elems)

    f32x4 acc[8][4] = {};
    bf16x8 af[4], bfr[4];

    auto stage = [&](int buf, int t, int r) {
        __builtin_amdgcn_global_load_lds(
            (const __attribute__((address_space(1))) void*)(gA0 + r * rstep + t * 32),
            (__attribute__((address_space(3))) void*)(sA + buf * 8192 + r * 4096 + ldsoff),
            16, 0, 0);
        __builtin_amdgcn_global_load_lds(
            (const __attribute__((address_space(1))) void*)(gB0 + r * rstep + t * 32),
            (__attribute__((address_space(3))) void*)(sB + buf * 8192 + r * 4096 + ldsoff),
            16, 0, 0);
    };

    const int NT = K >> 5;             // 32-wide K-tiles (64 here)

    // prologue: stage tiles 0,1 (8 loads); certify tile 0 (tile 1 in flight)
    stage(0, 0, 0); stage(0, 0, 1);
    stage(1, 1, 0); stage(1, 1, 1);
    asm volatile("s_waitcnt vmcnt(4)" ::: "memory");
    __builtin_amdgcn_s_barrier();

    int b0 = 0, bs = 2;
    for (int t = 0; t < NT; ++t) {
        const __bf16* pa = sA + b0 * 8192 + wm * (128 * 32);
        const __bf16* pb = sB + b0 * 8192 + wn * (64 * 32);
        const bool st = (t + 2) < NT;  // block-uniform

        // ---- phase 0: frags (fi 0-3) x (fj 0-3); 8 ds_reads ----
#pragma unroll
        for (int fi = 0; fi < 4; ++fi)
            af[fi] = *(const bf16x8*)(pa + (fi * 16 + ml) * 32 + coff);
#pragma unroll
        for (int fj = 0; fj < 4; ++fj)
            bfr[fj] = *(const bf16x8*)(pb + (fj * 16 + ml) * 32 + coff);
        if (st) stage(bs, t + 2, 0);
        __builtin_amdgcn_s_barrier();
        asm volatile("s_waitcnt lgkmcnt(0)" ::: "memory");
        __builtin_amdgcn_s_setprio(1);
#pragma unroll
        for (int fi = 0; fi < 4; ++fi)
#pragma unroll
            for (int fj = 0; fj < 4; ++fj)
                acc[fi][fj] = __builtin_amdgcn_mfma_f32_16x16x32_bf16(
                    af[fi], bfr[fj], acc[fi][fj], 0, 0, 0);
        __builtin_amdgcn_s_setprio(0);
        __builtin_amdgcn_s_barrier();

        // ---- phase 1: frags (fi 4-7) x (fj 0-3); 4 ds_reads (b reused) ----
#pragma unroll
        for (int fi = 0; fi < 4; ++fi)
            af[fi] = *(const bf16x8*)(pa + ((fi + 4) * 16 + ml) * 32 + coff);
        if (st) stage(bs, t + 2, 1);
        __builtin_amdgcn_s_barrier();
        asm volatile("s_waitcnt lgkmcnt(0)" ::: "memory");
        __builtin_amdgcn_s_setprio(1);
#pragma unroll
        for (int fi = 0; fi < 4; ++fi)
#pragma unroll
            for (int fj = 0; fj < 4; ++fj)
                acc[4 + fi][fj] = __builtin_amdgcn_mfma_f32_16x16x32_bf16(
                    af[fi], bfr[fj], acc[4 + fi][fj], 0, 0, 0);
        __builtin_amdgcn_s_setprio(0);
        // tile-boundary wait: certify tile t+1 (its 4 loads are the oldest);
        // tile t+2's 4 loads stay in flight. Never 0 until the tail.
        if (st)                { asm volatile("s_waitcnt vmcnt(4)" ::: "memory"); }
        else if (t + 1 < NT)   { asm volatile("s_waitcnt vmcnt(0)" ::: "memory"); }
        if (t + 1 < NT) __builtin_amdgcn_s_barrier();

        b0 = (b0 == 2) ? 0 : b0 + 1;
        bs = (bs == 2) ? 0 : bs + 1;
    }

    // epilogue
#pragma unroll
    for (int i = 0; i < 8; ++i)
#pragma unroll
        for (int j = 0; j < 4; ++j)
#pragma unroll
            for (int rg = 0; rg < 4; ++rg) {
                int row = m0 + wm * 128 + i * 16 + q * 4 + rg;
                int col = n0 + wn * 64 + j * 16 + ml;
                C[(long)row * N + col] = (CT)acc[i][j][rg];
            }
}

template <typename CT>
__global__ __launch_bounds__(512, 2)
void gemm_bt(const __bf16* __restrict__ A, const __bf16* __restrict__ Bt,
             CT* __restrict__ C, int M, int N, int K) {
    __shared__ __align__(16) __bf16 sA[3 * 8192];
    __shared__ __align__(16) __bf16 sB[3 * 8192];
    gemm_body<CT>(A, Bt, C, M, N, K, sA, sB);
}

// z-batched triple: v and r (bf16 out) + k (f32 out). One launch = 768
// blocks = exactly 3 full rounds of 256 CUs (no per-launch tail).
// Shared LDS declared once here -- both template instantiations use it
// (only one branch runs per block).
__global__ __launch_bounds__(512, 2)
void gemm3(const __bf16* __restrict__ Av, const __bf16* __restrict__ Ar,
           const __bf16* __restrict__ Ak,
           const __bf16* __restrict__ Bv, const __bf16* __restrict__ Br,
           const __bf16* __restrict__ Bk,
           __bf16* __restrict__ Cv, __bf16* __restrict__ Cr,
           float* __restrict__ Ck, int M, int N, int K) {
    __shared__ __align__(16) __bf16 sA[3 * 8192];
    __shared__ __align__(16) __bf16 sB[3 * 8192];
    if (blockIdx.z == 0)      gemm_body<__bf16>(Av, Bv, Cv, M, N, K, sA, sB);
    else if (blockIdx.z == 1) gemm_body<__bf16>(Ar, Br, Cr, M, N, K, sA, sB);
    else                      gemm_body<float>(Ak, Bk, Ck, M, N, K, sA, sB);
}

// ---------------------------------------------------------------------------
// Chunk-parallel WKV scan (C=32 -- r2's C=64 regressed, reverted).
// k f32, v/r bf16.
// ---------------------------------------------------------------------------
__global__ void wkv_pass1(const float* __restrict__ kk, const __bf16* __restrict__ vv,
                          const float* __restrict__ td,
                          float* __restrict__ al, float* __restrict__ bl,
                          float* __restrict__ el,
                          int Bn, int T, int D, int C, int L) {
    int gid = blockIdx.x * blockDim.x + threadIdx.x;
    int BD = Bn * D;
    if (gid >= BD * C) return;
    int c  = gid / BD;
    int bd = gid - c * BD;
    int b  = bd / D;
    int d  = bd - b * D;

    float w = __expf(td[d]);
    float alpha = 0.f, beta = 0.f, eps = -1e30f;
    long base = ((long)b * T + (long)c * L) * D + d;

    const int P = 8;
    float kb0[P], vb0[P], kb1[P], vb1[P];

    auto step = [&](float kt, float vt) {
        float ww2  = eps - w;
        float tau2 = fmaxf(ww2, kt);
        float e1b  = __expf(ww2 - tau2);
        float e2b  = __expf(kt - tau2);
        alpha = e1b * alpha + e2b * vt;
        beta  = e1b * beta + e2b;
        eps   = tau2;
    };

#pragma unroll
    for (int j = 0; j < P; ++j) {
        long o = base + (long)j * D;
        kb0[j] = kk[o]; vb0[j] = (float)vv[o];
    }
    for (int t0 = 0; t0 < L; t0 += 2 * P) {
#pragma unroll
        for (int j = 0; j < P; ++j) {
            long o = base + (long)(t0 + P + j) * D;
            kb1[j] = kk[o]; vb1[j] = (float)vv[o];
        }
#pragma unroll
        for (int j = 0; j < P; ++j) step(kb0[j], vb0[j]);
        if (t0 + 2 * P < L) {
#pragma unroll
            for (int j = 0; j < P; ++j) {
                long o = base + (long)(t0 + 2 * P + j) * D;
                kb0[j] = kk[o]; vb0[j] = (float)vv[o];
            }
        }
#pragma unroll
        for (int j = 0; j < P; ++j) step(kb1[j], vb1[j]);
    }
    al[gid] = alpha; bl[gid] = beta; el[gid] = eps;
}

__global__ void wkv_pass2(const float* __restrict__ kk, const __bf16* __restrict__ vv,
                          const __bf16* __restrict__ rr,
                          const float* __restrict__ td, const float* __restrict__ tf,
                          const float* __restrict__ al, const float* __restrict__ bl,
                          const float* __restrict__ el,
                          __bf16* __restrict__ out,
                          int Bn, int T, int D, int C, int L) {
    int gid = blockIdx.x * blockDim.x + threadIdx.x;
    int BD = Bn * D;
    if (gid >= BD * C) return;
    int c  = gid / BD;      // block-uniform (BD % 256 == 0)
    int bd = gid - c * BD;
    int b  = bd / D;
    int d  = bd - b * D;

    float u = tf[d];
    float w = __expf(td[d]);

    // --- fused combine: fold chunks 0..c-1 into this chunk's inbound state ---
    float alpha = 0.f, beta = 0.f, eps = -1e30f;
    {
        float wL = w * (float)L;
        for (int cc = 0; cc < c; ++cc) {
            int idx = cc * BD + bd;
            float ed  = eps - wL;
            float la = al[idx], lb = bl[idx], le = el[idx];
            float tau = fmaxf(ed, le);
            float e1  = __expf(ed - tau);
            float e2  = __expf(le - tau);
            alpha = alpha * e1 + la * e2;
            beta  = beta * e1 + lb * e2;
            eps   = tau;
        }
    }

    long base = ((long)b * T + (long)c * L) * D + d;

    const int P = 8;
    float kb0[P], vb0[P], rb0[P], kb1[P], vb1[P], rb1[P];

    auto step = [&](float kt, float vt, float rt, int tIdx) {
        float ww  = u + kt;
        float tau = fmaxf(eps, ww);
        float e1  = __expf(eps - tau);
        float e2  = __expf(ww - tau);
        float num = e1 * alpha + e2 * vt;
        float den = e1 * beta + e2;
        float o_  = num * __builtin_amdgcn_rcpf(den);
        float ww2  = eps - w;
        float tau2 = fmaxf(ww2, kt);
        float e1b  = __expf(ww2 - tau2);
        float e2b  = __expf(kt - tau2);
        alpha = e1b * alpha + e2b * vt;
        beta  = e1b * beta + e2b;
        eps   = tau2;
        float sr = __builtin_amdgcn_rcpf(1.0f + __expf(-rt));
        out[base + (long)tIdx * D] = (__bf16)(o_ * sr);
    };

#pragma unroll
    for (int j = 0; j < P; ++j) {
        long o = base + (long)j * D;
        kb0[j] = kk[o]; vb0[j] = (float)vv[o]; rb0[j] = (float)rr[o];
    }
    for (int t0 = 0; t0 < L; t0 += 2 * P) {
#pragma unroll
        for (int j = 0; j < P; ++j) {
            long o = base + (long)(t0 + P + j) * D;
            kb1[j] = kk[o]; vb1[j] = (float)vv[o]; rb1[j] = (float)rr[o];
        }
#pragma unroll
        for (int j = 0; j < P; ++j) step(kb0[j], vb0[j], rb0[j], t0 + j);
        if (t0 + 2 * P < L) {
#pragma unroll
            for (int j = 0; j < P; ++j) {
                long o = base + (long)(t0 + 2 * P + j) * D;
                kb0[j] = kk[o]; vb0[j] = (float)vv[o]; rb0[j] = (float)rr[o];
            }
        }
#pragma unroll
        for (int j = 0; j < P; ++j) step(kb1[j], vb1[j], rb1[j], t0 + P + j);
    }
}

// ---------------------------------------------------------------------------
extern "C" void kernel_launch(void* const* d_in, const int* in_sizes, int n_in,
                              void* d_out, int out_size, void* d_ws, size_t ws_size,
                              hipStream_t stream) {
    const float* x  = (const float*)d_in[0];
    const float* td = (const float*)d_in[1];
    const float* tf = (const float*)d_in[2];
    const float* mk = (const float*)d_in[3];
    const float* mv = (const float*)d_in[4];
    const float* mr = (const float*)d_in[5];
    const float* Wk = (const float*)d_in[6];
    const float* Wv = (const float*)d_in[7];
    const float* Wr = (const float*)d_in[8];
    const float* Wo = (const float*)d_in[9];
    float* out = (float*)d_out;

    const int D = in_sizes[1];                    // 2048
    const int T = 2048;
    const long total = (long)in_sizes[0];         // B*T*D
    const int Bn = (int)(total / ((long)T * D));  // 4
    const int M = Bn * T;
    const long DD = (long)D * D;
    const int C = 32;                             // scan chunks
    const int L = T / C;                          // 64
    const int BD = Bn * D;
    const int S = BD * C;

    // --- workspace layout ---
    // kf lives in d_out (dead until the final GEMM) because the merged
    // gemm3 runs k concurrently with v/r -- the old xmv/xmr overlay would race.
    char* p = (char*)d_ws;
    __bf16* xmk = (__bf16*)p;            p += total * 2;   // dead after gemm3
    __bf16* xmv = (__bf16*)p;            p += total * 2;   // dead after gemm3
    __bf16* xmr = (__bf16*)p;            p += total * 2;   // dead after gemm3
    __bf16* wkb = (__bf16*)p;            p += DD * 2;      // dead after gemm3
    __bf16* wvb = (__bf16*)p;            p += DD * 2;      // dead after gemm3
    __bf16* wrb = (__bf16*)p;            p += DD * 2;      // dead after gemm3
    __bf16* wob = (__bf16*)p;            p += DD * 2;      // live till end
    __bf16* vb  = (__bf16*)p;            p += total * 2;
    __bf16* rb  = (__bf16*)p;            p += total * 2;

    float*  kf = (float*)d_out;          // 64 MB scratch over the output buf
    __bf16* xo = xmk;                    // pass2 output over dead xmk
    float*  st = (float*)wkb;            // 3.1 MB scan state over dead wkb
    float *al = st, *bl = st + S, *el = st + 2 * S;

    unsigned cvtBlocks = (unsigned)((4 * DD / 8 + 255) / 256);
    unsigned mixBlocks = (unsigned)((total / 8 + 255) / 256);
    dim3 prepGrid(cvtBlocks + mixBlocks);
    dim3 gemm3Grid(D / 256, M / 256, 3);          // (8, 32, 3)
    dim3 gemmGrid(D / 256, M / 256);              // (8, 32)
    dim3 p12Grid((S + 255) / 256);

    prep_kernel<<<prepGrid, 256, 0, stream>>>(Wk, Wv, Wr, Wo, wkb, wvb, wrb, wob,
                                              DD, cvtBlocks,
                                              x, mk, mv, mr, xmk, xmv, xmr,
                                              T, D, total);

    gemm3<<<gemm3Grid, 512, 0, stream>>>(xmv, xmr, xmk, wvb, wrb, wkb,
                                         vb, rb, kf, M, D, D);

    wkv_pass1<<<p12Grid, 256, 0, stream>>>(kf, vb, td, al, bl, el, Bn, T, D, C, L);
    wkv_pass2<<<p12Grid, 256, 0, stream>>>(kf, vb, rb, td, tf, al, bl, el, xo,
                                           Bn, T, D, C, L);

    gemm_bt<float><<<gemmGrid, 512, 0, stream>>>(xo, wob, out, M, D, D);
}

// Round 5
// 514.449 us; speedup vs baseline: 1.0080x; 1.0080x over previous
//
#include <hip/hip_runtime.h>
#include <stdint.h>

typedef __bf16 bf16x8 __attribute__((ext_vector_type(8)));
typedef float f32x4 __attribute__((ext_vector_type(4)));

#define BM 128
#define BN 128
#define BK 64

// ---------------------------------------------------------------------------
// Fused prep: (a) f32->bf16 convert of the 4 weight matrices, (b) time-shift
// mix producing all three mixed A-matrices (bf16). Block-uniform branch.
// ---------------------------------------------------------------------------
__global__ void prep_kernel(const float* __restrict__ w0, const float* __restrict__ w1,
                            const float* __restrict__ w2, const float* __restrict__ w3,
                            __bf16* __restrict__ o0, __bf16* __restrict__ o1,
                            __bf16* __restrict__ o2, __bf16* __restrict__ o3,
                            long DD, unsigned cvtBlocks,
                            const float* __restrict__ x,
                            const float* __restrict__ mk, const float* __restrict__ mv,
                            const float* __restrict__ mr,
                            __bf16* __restrict__ ok, __bf16* __restrict__ ov,
                            __bf16* __restrict__ orr,
                            int T, int D, long total) {
    if (blockIdx.x < cvtBlocks) {
        long idx = ((long)blockIdx.x * blockDim.x + threadIdx.x) * 8;
        if (idx >= 4 * DD) return;
        int w = (int)(idx / DD);            // block-uniform (DD % 2048 == 0)
        long off = idx - (long)w * DD;
        const float* in = (w == 0) ? w0 : (w == 1) ? w1 : (w == 2) ? w2 : w3;
        __bf16* out     = (w == 0) ? o0 : (w == 1) ? o1 : (w == 2) ? o2 : o3;
        f32x4 a = *(const f32x4*)(in + off);
        f32x4 b = *(const f32x4*)(in + off + 4);
        bf16x8 o;
#pragma unroll
        for (int i = 0; i < 4; ++i) { o[i] = (__bf16)a[i]; o[i + 4] = (__bf16)b[i]; }
        *(bf16x8*)(out + off) = o;
    } else {
        long idx = ((long)(blockIdx.x - cvtBlocks) * blockDim.x + threadIdx.x) * 8;
        if (idx >= total) return;
        int d = (int)(idx % D);
        long bt = idx / D;
        int t = (int)(bt % T);

        f32x4 x0 = *(const f32x4*)(x + idx);
        f32x4 x1 = *(const f32x4*)(x + idx + 4);
        f32x4 l0 = {}, l1 = {};
        if (t != 0) {
            l0 = *(const f32x4*)(x + idx - D);
            l1 = *(const f32x4*)(x + idx - D + 4);
        }
        const float* mw[3] = {mk, mv, mr};
        __bf16* ow[3] = {ok, ov, orr};
#pragma unroll
        for (int s = 0; s < 3; ++s) {
            f32x4 m0 = *(const f32x4*)(mw[s] + d);
            f32x4 m1 = *(const f32x4*)(mw[s] + d + 4);
            bf16x8 o;
#pragma unroll
            for (int i = 0; i < 4; ++i) {
                o[i]     = (__bf16)(x0[i] * m0[i] + l0[i] * (1.0f - m0[i]));
                o[i + 4] = (__bf16)(x1[i] * m1[i] + l1[i] * (1.0f - m1[i]));
            }
            *(bf16x8*)(ow[s] + idx) = o;
        }
    }
}

// ---------------------------------------------------------------------------
// GEMM body: m97-ladder 128x128 structure + T1 XCD swizzle (r2, verified
// 1032 TF / 133 us for the bt2 pair). Rounds 1/3/4 pipeline rewrites all
// measured slower (877-908 TF) -> this body is final for this session.
// ---------------------------------------------------------------------------
template <typename CT>
__device__ __attribute__((always_inline))
void gemm_body(const __bf16* __restrict__ A, const __bf16* __restrict__ Bt,
               CT* __restrict__ C, int M, int N, int K) {
    __shared__ __align__(16) __bf16 sA[BM * BK];
    __shared__ __align__(16) __bf16 sB[BN * BK];

    const int tid  = threadIdx.x;
    const int lane = tid & 63;
    const int wave = tid >> 6;

    // T1: XCD-aware bijective swizzle (nwg = 1024 per z-slice, % 8 == 0)
    const int id  = blockIdx.y * gridDim.x + blockIdx.x;
    const int nwg = gridDim.x * gridDim.y;
    const int wg  = (id & 7) * (nwg >> 3) + (id >> 3);
    const int bx  = wg % gridDim.x;
    const int by  = wg / gridDim.x;
    const int m0 = by * BM;
    const int n0 = bx * BN;

    const int wm = (wave & 1) * 64;
    const int wn = (wave >> 1) * 64;

    const int l8 = lane >> 3;
    const int c8 = lane & 7;
    const int cg = c8 ^ l8;

    const int q  = lane >> 4;
    const int ml = lane & 15;

    f32x4 acc[4][4] = {};

    for (int k0 = 0; k0 < K; k0 += BK) {
#pragma unroll
        for (int i = 0; i < 4; ++i) {
            const int cl  = wave * 4 + i;
            const int row = cl * 8 + l8;
            const __bf16* gA = A  + (long)(m0 + row) * K + (k0 + cg * 8);
            const __bf16* gB = Bt + (long)(n0 + row) * K + (k0 + cg * 8);
            __builtin_amdgcn_global_load_lds(
                (const __attribute__((address_space(1))) void*)gA,
                (__attribute__((address_space(3))) void*)(sA + cl * 512), 16, 0, 0);
            __builtin_amdgcn_global_load_lds(
                (const __attribute__((address_space(1))) void*)gB,
                (__attribute__((address_space(3))) void*)(sB + cl * 512), 16, 0, 0);
        }
        __syncthreads();

#pragma unroll
        for (int kk = 0; kk < BK; kk += 32) {
            bf16x8 af[4], bfr[4];
#pragma unroll
            for (int i = 0; i < 4; ++i) {
                int row = wm + i * 16 + ml;
                int cl  = ((kk >> 3) + q) ^ (row & 7);
                af[i] = *(const bf16x8*)(sA + row * BK + cl * 8);
            }
#pragma unroll
            for (int j = 0; j < 4; ++j) {
                int row = wn + j * 16 + ml;
                int cl  = ((kk >> 3) + q) ^ (row & 7);
                bfr[j] = *(const bf16x8*)(sB + row * BK + cl * 8);
            }
#pragma unroll
            for (int i = 0; i < 4; ++i)
#pragma unroll
                for (int j = 0; j < 4; ++j)
                    acc[i][j] = __builtin_amdgcn_mfma_f32_16x16x32_bf16(
                        af[i], bfr[j], acc[i][j], 0, 0, 0);
        }
        __syncthreads();
    }

#pragma unroll
    for (int i = 0; i < 4; ++i)
#pragma unroll
        for (int j = 0; j < 4; ++j)
#pragma unroll
            for (int rg = 0; rg < 4; ++rg) {
                int row = m0 + wm + i * 16 + q * 4 + rg;
                int col = n0 + wn + j * 16 + ml;
                C[(long)row * N + col] = (CT)acc[i][j][rg];
            }
}

template <typename CT>
__global__ __launch_bounds__(256, 3)
void gemm_bt(const __bf16* __restrict__ A, const __bf16* __restrict__ Bt,
             CT* __restrict__ C, int M, int N, int K) {
    gemm_body<CT>(A, Bt, C, M, N, K);
}

// z-batched pair (v and r GEMMs), both bf16 outputs (same instantiation).
__global__ __launch_bounds__(256, 3)
void gemm_bt2(const __bf16* __restrict__ A0, const __bf16* __restrict__ A1,
              const __bf16* __restrict__ B0, const __bf16* __restrict__ B1,
              __bf16* __restrict__ C0, __bf16* __restrict__ C1,
              int M, int N, int K) {
    if (blockIdx.z == 0) gemm_body<__bf16>(A0, B0, C0, M, N, K);
    else                 gemm_body<__bf16>(A1, B1, C1, M, N, K);
}

// ---------------------------------------------------------------------------
// Chunk-parallel WKV scan, C=64 (L=32) with a SEPARATE combine kernel.
// r2's C=64 failed because every pass2 thread carried an O(C) fold; now the
// fold runs once per (b,d) column in wkv_combine (8192 threads, ~us), and
// both passes get full-machine occupancy (524k threads) + half the serial
// chain vs C=32. Arithmetic and fold order identical to the old in-thread
// version -> bitwise-same numerics.
// ---------------------------------------------------------------------------
__global__ void wkv_pass1(const float* __restrict__ kk, const __bf16* __restrict__ vv,
                          const float* __restrict__ td,
                          float* __restrict__ al, float* __restrict__ bl,
                          float* __restrict__ el,
                          int Bn, int T, int D, int C, int L) {
    int gid = blockIdx.x * blockDim.x + threadIdx.x;
    int BD = Bn * D;
    if (gid >= BD * C) return;
    int c  = gid / BD;
    int bd = gid - c * BD;
    int b  = bd / D;
    int d  = bd - b * D;

    float w = __expf(td[d]);
    float alpha = 0.f, beta = 0.f, eps = -1e30f;
    long base = ((long)b * T + (long)c * L) * D + d;

    const int P = 8;
    float kb0[P], vb0[P], kb1[P], vb1[P];

    auto step = [&](float kt, float vt) {
        float ww2  = eps - w;
        float tau2 = fmaxf(ww2, kt);
        float e1b  = __expf(ww2 - tau2);
        float e2b  = __expf(kt - tau2);
        alpha = e1b * alpha + e2b * vt;
        beta  = e1b * beta + e2b;
        eps   = tau2;
    };

#pragma unroll
    for (int j = 0; j < P; ++j) {
        long o = base + (long)j * D;
        kb0[j] = kk[o]; vb0[j] = (float)vv[o];
    }
    for (int t0 = 0; t0 < L; t0 += 2 * P) {
#pragma unroll
        for (int j = 0; j < P; ++j) {
            long o = base + (long)(t0 + P + j) * D;
            kb1[j] = kk[o]; vb1[j] = (float)vv[o];
        }
#pragma unroll
        for (int j = 0; j < P; ++j) step(kb0[j], vb0[j]);
        if (t0 + 2 * P < L) {
#pragma unroll
            for (int j = 0; j < P; ++j) {
                long o = base + (long)(t0 + 2 * P + j) * D;
                kb0[j] = kk[o]; vb0[j] = (float)vv[o];
            }
        }
#pragma unroll
        for (int j = 0; j < P; ++j) step(kb1[j], vb1[j]);
    }
    al[gid] = alpha; bl[gid] = beta; el[gid] = eps;
}

// Exclusive prefix over chunks, in place: slot (c,bd) goes from chunk-local
// state to the INBOUND state for chunk c. One thread per (b,d) column,
// sequential over C chunks (coalesced across bd), P-batched loads.
__global__ void wkv_combine(float* __restrict__ al, float* __restrict__ bl,
                            float* __restrict__ el,
                            const float* __restrict__ td,
                            int BD, int D, int C, int L) {
    int bd = blockIdx.x * blockDim.x + threadIdx.x;
    if (bd >= BD) return;
    int d = bd % D;
    float wL = __expf(td[d]) * (float)L;

    float pa = 0.f, pb = 0.f, pe = -1e30f;
    const int P = 8;
    float la[P], lb[P], le[P];
    for (int c0 = 0; c0 < C; c0 += P) {
#pragma unroll
        for (int j = 0; j < P; ++j) {
            int idx = (c0 + j) * BD + bd;
            la[j] = al[idx]; lb[j] = bl[idx]; le[j] = el[idx];
        }
#pragma unroll
        for (int j = 0; j < P; ++j) {
            int idx = (c0 + j) * BD + bd;
            al[idx] = pa; bl[idx] = pb; el[idx] = pe;   // exclusive prefix
            float ed  = pe - wL;
            float tau = fmaxf(ed, le[j]);
            float e1  = __expf(ed - tau);
            float e2  = __expf(le[j] - tau);
            pa = pa * e1 + la[j] * e2;
            pb = pb * e1 + lb[j] * e2;
            pe = tau;
        }
    }
}

__global__ void wkv_pass2(const float* __restrict__ kk, const __bf16* __restrict__ vv,
                          const __bf16* __restrict__ rr,
                          const float* __restrict__ td, const float* __restrict__ tf,
                          const float* __restrict__ al, const float* __restrict__ bl,
                          const float* __restrict__ el,
                          __bf16* __restrict__ out,
                          int Bn, int T, int D, int C, int L) {
    int gid = blockIdx.x * blockDim.x + threadIdx.x;
    int BD = Bn * D;
    if (gid >= BD * C) return;
    int c  = gid / BD;      // block-uniform (BD % 256 == 0)
    int bd = gid - c * BD;
    int b  = bd / D;
    int d  = bd - b * D;

    float u = tf[d];
    float w = __expf(td[d]);

    // inbound state precomputed by wkv_combine (exclusive prefix)
    float alpha = al[gid], beta = bl[gid], eps = el[gid];

    long base = ((long)b * T + (long)c * L) * D + d;

    const int P = 8;
    float kb0[P], vb0[P], rb0[P], kb1[P], vb1[P], rb1[P];

    auto step = [&](float kt, float vt, float rt, int tIdx) {
        float ww  = u + kt;
        float tau = fmaxf(eps, ww);
        float e1  = __expf(eps - tau);
        float e2  = __expf(ww - tau);
        float num = e1 * alpha + e2 * vt;
        float den = e1 * beta + e2;
        float o_  = num * __builtin_amdgcn_rcpf(den);
        float ww2  = eps - w;
        float tau2 = fmaxf(ww2, kt);
        float e1b  = __expf(ww2 - tau2);
        float e2b  = __expf(kt - tau2);
        alpha = e1b * alpha + e2b * vt;
        beta  = e1b * beta + e2b;
        eps   = tau2;
        float sr = __builtin_amdgcn_rcpf(1.0f + __expf(-rt));
        out[base + (long)tIdx * D] = (__bf16)(o_ * sr);
    };

#pragma unroll
    for (int j = 0; j < P; ++j) {
        long o = base + (long)j * D;
        kb0[j] = kk[o]; vb0[j] = (float)vv[o]; rb0[j] = (float)rr[o];
    }
    for (int t0 = 0; t0 < L; t0 += 2 * P) {
#pragma unroll
        for (int j = 0; j < P; ++j) {
            long o = base + (long)(t0 + P + j) * D;
            kb1[j] = kk[o]; vb1[j] = (float)vv[o]; rb1[j] = (float)rr[o];
        }
#pragma unroll
        for (int j = 0; j < P; ++j) step(kb0[j], vb0[j], rb0[j], t0 + j);
        if (t0 + 2 * P < L) {
#pragma unroll
            for (int j = 0; j < P; ++j) {
                long o = base + (long)(t0 + 2 * P + j) * D;
                kb0[j] = kk[o]; vb0[j] = (float)vv[o]; rb0[j] = (float)rr[o];
            }
        }
#pragma unroll
        for (int j = 0; j < P; ++j) step(kb1[j], vb1[j], rb1[j], t0 + P + j);
    }
}

// ---------------------------------------------------------------------------
extern "C" void kernel_launch(void* const* d_in, const int* in_sizes, int n_in,
                              void* d_out, int out_size, void* d_ws, size_t ws_size,
                              hipStream_t stream) {
    const float* x  = (const float*)d_in[0];
    const float* td = (const float*)d_in[1];
    const float* tf = (const float*)d_in[2];
    const float* mk = (const float*)d_in[3];
    const float* mv = (const float*)d_in[4];
    const float* mr = (const float*)d_in[5];
    const float* Wk = (const float*)d_in[6];
    const float* Wv = (const float*)d_in[7];
    const float* Wr = (const float*)d_in[8];
    const float* Wo = (const float*)d_in[9];
    float* out = (float*)d_out;

    const int D = in_sizes[1];                    // 2048
    const int T = 2048;
    const long total = (long)in_sizes[0];         // B*T*D
    const int Bn = (int)(total / ((long)T * D));  // 4
    const int M = Bn * T;
    const long DD = (long)D * D;
    const int C = 64;                             // scan chunks (combine is now a separate kernel)
    const int L = T / C;                          // 32
    const int BD = Bn * D;
    const int S = BD * C;

    // --- workspace layout (r2 layout; aliasing relies on stream order) ---
    char* p = (char*)d_ws;
    __bf16* xmk = (__bf16*)p;            p += total * 2;   // dead after gemm_k
    __bf16* xmv = (__bf16*)p;            p += total * 2;   // dead after gemm_bt2
    __bf16* xmr = (__bf16*)p;            p += total * 2;   // dead after gemm_bt2
    __bf16* wkb = (__bf16*)p;            p += DD * 2;      // dead after gemm_k
    __bf16* wvb = (__bf16*)p;            p += DD * 2;      // dead after gemm_bt2
    __bf16* wrb = (__bf16*)p;            p += DD * 2;      // dead after gemm_bt2
    __bf16* wob = (__bf16*)p;            p += DD * 2;      // live till end
    __bf16* vb  = (__bf16*)p;            p += total * 2;
    __bf16* rb  = (__bf16*)p;            p += total * 2;

    float*  kf = (float*)xmv;            // 64 MB over dead xmv+xmr
    __bf16* xo = xmk;                    // pass2 output over dead xmk
    float*  st = (float*)wkb;            // 6.3 MB scan state over dead wkb
    float *al = st, *bl = st + S, *el = st + 2 * S;

    unsigned cvtBlocks = (unsigned)((4 * DD / 8 + 255) / 256);
    unsigned mixBlocks = (unsigned)((total / 8 + 255) / 256);
    dim3 prepGrid(cvtBlocks + mixBlocks);
    dim3 gemmGrid(D / BN, M / BM);                // (16, 64)
    dim3 gemm2Grid(D / BN, M / BM, 2);
    dim3 p12Grid((S + 255) / 256);                // 2048 blocks
    dim3 cmbGrid((BD + 255) / 256);               // 32 blocks

    prep_kernel<<<prepGrid, 256, 0, stream>>>(Wk, Wv, Wr, Wo, wkb, wvb, wrb, wob,
                                              DD, cvtBlocks,
                                              x, mk, mv, mr, xmk, xmv, xmr,
                                              T, D, total);

    // v and r GEMMs first (they consume xmv/xmr, freeing the space kf reuses)
    gemm_bt2<<<gemm2Grid, 256, 0, stream>>>(xmv, xmr, wvb, wrb, vb, rb, M, D, D);
    gemm_bt<float><<<gemmGrid, 256, 0, stream>>>(xmk, wkb, kf, M, D, D);

    wkv_pass1<<<p12Grid, 256, 0, stream>>>(kf, vb, td, al, bl, el, Bn, T, D, C, L);
    wkv_combine<<<cmbGrid, 256, 0, stream>>>(al, bl, el, td, BD, D, C, L);
    wkv_pass2<<<p12Grid, 256, 0, stream>>>(kf, vb, rb, td, tf, al, bl, el, xo,
                                           Bn, T, D, C, L);

    gemm_bt<float><<<gemmGrid, 256, 0, stream>>>(xo, wob, out, M, D, D);
}

// Round 7
// 495.319 us; speedup vs baseline: 1.0469x; 1.0386x over previous
//
#include <hip/hip_runtime.h>
#include <stdint.h>

typedef __bf16 bf16x8 __attribute__((ext_vector_type(8)));
typedef float f32x4 __attribute__((ext_vector_type(4)));

#define BM 128
#define BN 128
#define BK 64

// Fixed problem shape (harness-constant across all rounds): B=4, T=D=2048.
// All div/mod by these are compile-time shifts/masks -- gfx950 has no integer
// divide; runtime-divisor div/mod compiles to long software sequences.
constexpr int  DC  = 2048;
constexpr int  TC  = 2048;
constexpr long DDC = (long)DC * DC;          // 2^22
constexpr int  BnC = 4;
constexpr int  BDC = BnC * DC;               // 8192 = 2^13
constexpr int  CC  = 64;                     // scan chunks
constexpr int  LC  = TC / CC;                // 32

// ---------------------------------------------------------------------------
// Fused prep: (a) f32->bf16 convert of the 4 weight matrices, (b) time-shift
// mix producing all three mixed A-matrices (bf16). Block-uniform branch.
// ---------------------------------------------------------------------------
__global__ void prep_kernel(const float* __restrict__ w0, const float* __restrict__ w1,
                            const float* __restrict__ w2, const float* __restrict__ w3,
                            __bf16* __restrict__ o0, __bf16* __restrict__ o1,
                            __bf16* __restrict__ o2, __bf16* __restrict__ o3,
                            unsigned cvtBlocks,
                            const float* __restrict__ x,
                            const float* __restrict__ mk, const float* __restrict__ mv,
                            const float* __restrict__ mr,
                            __bf16* __restrict__ ok, __bf16* __restrict__ ov,
                            __bf16* __restrict__ orr,
                            long total) {
    if (blockIdx.x < cvtBlocks) {
        long idx = ((long)blockIdx.x * blockDim.x + threadIdx.x) * 8;
        if (idx >= 4 * DDC) return;
        int w = (int)(idx >> 22);           // idx / DDC (block-uniform)
        long off = idx & (DDC - 1);         // idx % DDC
        const float* in = (w == 0) ? w0 : (w == 1) ? w1 : (w == 2) ? w2 : w3;
        __bf16* out     = (w == 0) ? o0 : (w == 1) ? o1 : (w == 2) ? o2 : o3;
        f32x4 a = *(const f32x4*)(in + off);
        f32x4 b = *(const f32x4*)(in + off + 4);
        bf16x8 o;
#pragma unroll
        for (int i = 0; i < 4; ++i) { o[i] = (__bf16)a[i]; o[i + 4] = (__bf16)b[i]; }
        *(bf16x8*)(out + off) = o;
    } else {
        long idx = ((long)(blockIdx.x - cvtBlocks) * blockDim.x + threadIdx.x) * 8;
        if (idx >= total) return;
        int d = (int)(idx & (DC - 1));      // idx % D
        long bt = idx >> 11;                // idx / D
        int t = (int)(bt & (TC - 1));       // bt % T

        f32x4 x0 = *(const f32x4*)(x + idx);
        f32x4 x1 = *(const f32x4*)(x + idx + 4);
        f32x4 l0 = {}, l1 = {};
        if (t != 0) {
            l0 = *(const f32x4*)(x + idx - DC);
            l1 = *(const f32x4*)(x + idx - DC + 4);
        }
        const float* mw[3] = {mk, mv, mr};
        __bf16* ow[3] = {ok, ov, orr};
#pragma unroll
        for (int s = 0; s < 3; ++s) {
            f32x4 m0 = *(const f32x4*)(mw[s] + d);
            f32x4 m1 = *(const f32x4*)(mw[s] + d + 4);
            bf16x8 o;
#pragma unroll
            for (int i = 0; i < 4; ++i) {
                o[i]     = (__bf16)(x0[i] * m0[i] + l0[i] * (1.0f - m0[i]));
                o[i + 4] = (__bf16)(x1[i] * m1[i] + l1[i] * (1.0f - m1[i]));
            }
            *(bf16x8*)(ow[s] + idx) = o;
        }
    }
}

// ---------------------------------------------------------------------------
// GEMM body: m97-ladder 128x128 structure + T1 XCD swizzle (r2, verified
// 1032 TF / 133 us for the bt2 pair). Pipeline rewrites (r1/r3/r4) all
// measured slower -> structure frozen. r6: __launch_bounds__(256,4) -- the
// HW allows 4 blocks/CU (128 unified regs/thread, 128 KiB LDS) but (256,3)
// was artificially capping occupancy at 3; the 4th resident block gives the
// cross-block overlap (m114) that covers the pre-barrier vmcnt drain.
// ---------------------------------------------------------------------------
template <typename CT>
__device__ __attribute__((always_inline))
void gemm_body(const __bf16* __restrict__ A, const __bf16* __restrict__ Bt,
               CT* __restrict__ C, int M, int N, int K) {
    __shared__ __align__(16) __bf16 sA[BM * BK];
    __shared__ __align__(16) __bf16 sB[BN * BK];

    const int tid  = threadIdx.x;
    const int lane = tid & 63;
    const int wave = tid >> 6;

    // T1: XCD-aware bijective swizzle; grid is always (16, 64) here.
    const int id  = blockIdx.y * 16 + blockIdx.x;
    const int wg  = (id & 7) * 128 + (id >> 3);     // nwg=1024
    const int bx  = wg & 15;
    const int by  = wg >> 4;
    const int m0 = by * BM;
    const int n0 = bx * BN;

    const int wm = (wave & 1) * 64;
    const int wn = (wave >> 1) * 64;

    const int l8 = lane >> 3;
    const int c8 = lane & 7;
    const int cg = c8 ^ l8;

    const int q  = lane >> 4;
    const int ml = lane & 15;

    f32x4 acc[4][4] = {};

    for (int k0 = 0; k0 < K; k0 += BK) {
#pragma unroll
        for (int i = 0; i < 4; ++i) {
            const int cl  = wave * 4 + i;
            const int row = cl * 8 + l8;
            const __bf16* gA = A  + (long)(m0 + row) * K + (k0 + cg * 8);
            const __bf16* gB = Bt + (long)(n0 + row) * K + (k0 + cg * 8);
            __builtin_amdgcn_global_load_lds(
                (const __attribute__((address_space(1))) void*)gA,
                (__attribute__((address_space(3))) void*)(sA + cl * 512), 16, 0, 0);
            __builtin_amdgcn_global_load_lds(
                (const __attribute__((address_space(1))) void*)gB,
                (__attribute__((address_space(3))) void*)(sB + cl * 512), 16, 0, 0);
        }
        __syncthreads();

#pragma unroll
        for (int kk = 0; kk < BK; kk += 32) {
            bf16x8 af[4], bfr[4];
#pragma unroll
            for (int i = 0; i < 4; ++i) {
                int row = wm + i * 16 + ml;
                int cl  = ((kk >> 3) + q) ^ (row & 7);
                af[i] = *(const bf16x8*)(sA + row * BK + cl * 8);
            }
#pragma unroll
            for (int j = 0; j < 4; ++j) {
                int row = wn + j * 16 + ml;
                int cl  = ((kk >> 3) + q) ^ (row & 7);
                bfr[j] = *(const bf16x8*)(sB + row * BK + cl * 8);
            }
#pragma unroll
            for (int i = 0; i < 4; ++i)
#pragma unroll
                for (int j = 0; j < 4; ++j)
                    acc[i][j] = __builtin_amdgcn_mfma_f32_16x16x32_bf16(
                        af[i], bfr[j], acc[i][j], 0, 0, 0);
        }
        __syncthreads();
    }

#pragma unroll
    for (int i = 0; i < 4; ++i)
#pragma unroll
        for (int j = 0; j < 4; ++j)
#pragma unroll
            for (int rg = 0; rg < 4; ++rg) {
                int row = m0 + wm + i * 16 + q * 4 + rg;
                int col = n0 + wn + j * 16 + ml;
                C[(long)row * N + col] = (CT)acc[i][j][rg];
            }
}

template <typename CT>
__global__ __launch_bounds__(256, 4)
void gemm_bt(const __bf16* __restrict__ A, const __bf16* __restrict__ Bt,
             CT* __restrict__ C, int M, int N, int K) {
    gemm_body<CT>(A, Bt, C, M, N, K);
}

// z-batched pair (v and r GEMMs), both bf16 outputs (same instantiation).
__global__ __launch_bounds__(256, 4)
void gemm_bt2(const __bf16* __restrict__ A0, const __bf16* __restrict__ A1,
              const __bf16* __restrict__ B0, const __bf16* __restrict__ B1,
              __bf16* __restrict__ C0, __bf16* __restrict__ C1,
              int M, int N, int K) {
    if (blockIdx.z == 0) gemm_body<__bf16>(A0, B0, C0, M, N, K);
    else                 gemm_body<__bf16>(A1, B1, C1, M, N, K);
}

// ---------------------------------------------------------------------------
// Chunk-parallel WKV scan, C=64 (L=32), separate exclusive-prefix combine.
// All index div/mod are constexpr shifts now (no HW integer divide).
// ---------------------------------------------------------------------------
__global__ void wkv_pass1(const float* __restrict__ kk, const __bf16* __restrict__ vv,
                          const float* __restrict__ td,
                          float* __restrict__ al, float* __restrict__ bl,
                          float* __restrict__ el) {
    int gid = blockIdx.x * blockDim.x + threadIdx.x;
    if (gid >= BDC * CC) return;
    int c  = gid >> 13;                 // gid / BD
    int bd = gid & (BDC - 1);
    int b  = bd >> 11;                  // bd / D
    int d  = bd & (DC - 1);

    float w = __expf(td[d]);
    float alpha = 0.f, beta = 0.f, eps = -1e30f;
    long base = ((long)b * TC + (long)c * LC) * DC + d;

    const int P = 8;
    float kb0[P], vb0[P], kb1[P], vb1[P];

    auto step = [&](float kt, float vt) {
        float ww2  = eps - w;
        float tau2 = fmaxf(ww2, kt);
        float e1b  = __expf(ww2 - tau2);
        float e2b  = __expf(kt - tau2);
        alpha = e1b * alpha + e2b * vt;
        beta  = e1b * beta + e2b;
        eps   = tau2;
    };

#pragma unroll
    for (int j = 0; j < P; ++j) {
        long o = base + (long)j * DC;
        kb0[j] = kk[o]; vb0[j] = (float)vv[o];
    }
    for (int t0 = 0; t0 < LC; t0 += 2 * P) {
#pragma unroll
        for (int j = 0; j < P; ++j) {
            long o = base + (long)(t0 + P + j) * DC;
            kb1[j] = kk[o]; vb1[j] = (float)vv[o];
        }
#pragma unroll
        for (int j = 0; j < P; ++j) step(kb0[j], vb0[j]);
        if (t0 + 2 * P < LC) {
#pragma unroll
            for (int j = 0; j < P; ++j) {
                long o = base + (long)(t0 + 2 * P + j) * DC;
                kb0[j] = kk[o]; vb0[j] = (float)vv[o];
            }
        }
#pragma unroll
        for (int j = 0; j < P; ++j) step(kb1[j], vb1[j]);
    }
    al[gid] = alpha; bl[gid] = beta; el[gid] = eps;
}

// Exclusive prefix over chunks, in place. One thread per (b,d) column,
// sequential over C chunks (coalesced across bd), P-batched loads.
__global__ void wkv_combine(float* __restrict__ al, float* __restrict__ bl,
                            float* __restrict__ el,
                            const float* __restrict__ td) {
    int bd = blockIdx.x * blockDim.x + threadIdx.x;
    if (bd >= BDC) return;
    int d = bd & (DC - 1);
    float wL = __expf(td[d]) * (float)LC;

    float pa = 0.f, pb = 0.f, pe = -1e30f;
    const int P = 8;
    float la[P], lb[P], le[P];
    for (int c0 = 0; c0 < CC; c0 += P) {
#pragma unroll
        for (int j = 0; j < P; ++j) {
            int idx = (c0 + j) * BDC + bd;
            la[j] = al[idx]; lb[j] = bl[idx]; le[j] = el[idx];
        }
#pragma unroll
        for (int j = 0; j < P; ++j) {
            int idx = (c0 + j) * BDC + bd;
            al[idx] = pa; bl[idx] = pb; el[idx] = pe;   // exclusive prefix
            float ed  = pe - wL;
            float tau = fmaxf(ed, le[j]);
            float e1  = __expf(ed - tau);
            float e2  = __expf(le[j] - tau);
            pa = pa * e1 + la[j] * e2;
            pb = pb * e1 + lb[j] * e2;
            pe = tau;
        }
    }
}

__global__ void wkv_pass2(const float* __restrict__ kk, const __bf16* __restrict__ vv,
                          const __bf16* __restrict__ rr,
                          const float* __restrict__ td, const float* __restrict__ tf,
                          const float* __restrict__ al, const float* __restrict__ bl,
                          const float* __restrict__ el,
                          __bf16* __restrict__ out) {
    int gid = blockIdx.x * blockDim.x + threadIdx.x;
    if (gid >= BDC * CC) return;
    int c  = gid >> 13;                 // gid / BD (block-uniform)
    int bd = gid & (BDC - 1);
    int b  = bd >> 11;
    int d  = bd & (DC - 1);

    float u = tf[d];
    float w = __expf(td[d]);

    // inbound state precomputed by wkv_combine (exclusive prefix)
    float alpha = al[gid], beta = bl[gid], eps = el[gid];

    long base = ((long)b * TC + (long)c * LC) * DC + d;

    const int P = 8;
    float kb0[P], vb0[P], rb0[P], kb1[P], vb1[P], rb1[P];

    auto step = [&](float kt, float vt, float rt, int tIdx) {
        float ww  = u + kt;
        float tau = fmaxf(eps, ww);
        float e1  = __expf(eps - tau);
        float e2  = __expf(ww - tau);
        float num = e1 * alpha + e2 * vt;
        float den = e1 * beta + e2;
        float o_  = num * __builtin_amdgcn_rcpf(den);
        float ww2  = eps - w;
        float tau2 = fmaxf(ww2, kt);
        float e1b  = __expf(ww2 - tau2);
        float e2b  = __expf(kt - tau2);
        alpha = e1b * alpha + e2b * vt;
        beta  = e1b * beta + e2b;
        eps   = tau2;
        float sr = __builtin_amdgcn_rcpf(1.0f + __expf(-rt));
        out[base + (long)tIdx * DC] = (__bf16)(o_ * sr);
    };

#pragma unroll
    for (int j = 0; j < P; ++j) {
        long o = base + (long)j * DC;
        kb0[j] = kk[o]; vb0[j] = (float)vv[o]; rb0[j] = (float)rr[o];
    }
    for (int t0 = 0; t0 < LC; t0 += 2 * P) {
#pragma unroll
        for (int j = 0; j < P; ++j) {
            long o = base + (long)(t0 + P + j) * DC;
            kb1[j] = kk[o]; vb1[j] = (float)vv[o]; rb1[j] = (float)rr[o];
        }
#pragma unroll
        for (int j = 0; j < P; ++j) step(kb0[j], vb0[j], rb0[j], t0 + j);
        if (t0 + 2 * P < LC) {
#pragma unroll
            for (int j = 0; j < P; ++j) {
                long o = base + (long)(t0 + 2 * P + j) * DC;
                kb0[j] = kk[o]; vb0[j] = (float)vv[o]; rb0[j] = (float)rr[o];
            }
        }
#pragma unroll
        for (int j = 0; j < P; ++j) step(kb1[j], vb1[j], rb1[j], t0 + P + j);
    }
}

// ---------------------------------------------------------------------------
extern "C" void kernel_launch(void* const* d_in, const int* in_sizes, int n_in,
                              void* d_out, int out_size, void* d_ws, size_t ws_size,
                              hipStream_t stream) {
    const float* x  = (const float*)d_in[0];
    const float* td = (const float*)d_in[1];
    const float* tf = (const float*)d_in[2];
    const float* mk = (const float*)d_in[3];
    const float* mv = (const float*)d_in[4];
    const float* mr = (const float*)d_in[5];
    const float* Wk = (const float*)d_in[6];
    const float* Wv = (const float*)d_in[7];
    const float* Wr = (const float*)d_in[8];
    const float* Wo = (const float*)d_in[9];
    float* out = (float*)d_out;

    const int D = DC;
    const int T = TC;
    const long total = (long)in_sizes[0];         // B*T*D = 16.7M
    const int M = BnC * T;                        // 8192
    const long DD = DDC;
    const int S = BDC * CC;

    // --- workspace layout (aliasing relies on stream order) ---
    char* p = (char*)d_ws;
    __bf16* xmk = (__bf16*)p;            p += total * 2;   // dead after gemm_k
    __bf16* xmv = (__bf16*)p;            p += total * 2;   // dead after gemm_bt2
    __bf16* xmr = (__bf16*)p;            p += total * 2;   // dead after gemm_bt2
    __bf16* wkb = (__bf16*)p;            p += DD * 2;      // dead after gemm_k
    __bf16* wvb = (__bf16*)p;            p += DD * 2;      // dead after gemm_bt2
    __bf16* wrb = (__bf16*)p;            p += DD * 2;      // dead after gemm_bt2
    __bf16* wob = (__bf16*)p;            p += DD * 2;      // live till end
    __bf16* vb  = (__bf16*)p;            p += total * 2;
    __bf16* rb  = (__bf16*)p;            p += total * 2;

    float*  kf = (float*)xmv;            // 64 MB over dead xmv+xmr
    __bf16* xo = xmk;                    // pass2 output over dead xmk
    float*  st = (float*)wkb;            // 6.3 MB scan state over dead wkb
    float *al = st, *bl = st + S, *el = st + 2 * S;

    unsigned cvtBlocks = (unsigned)((4 * DD / 8 + 255) / 256);
    unsigned mixBlocks = (unsigned)((total / 8 + 255) / 256);
    dim3 prepGrid(cvtBlocks + mixBlocks);
    dim3 gemmGrid(D / BN, M / BM);                // (16, 64)
    dim3 gemm2Grid(D / BN, M / BM, 2);
    dim3 p12Grid((S + 255) / 256);                // 2048 blocks
    dim3 cmbGrid((BDC + 255) / 256);              // 32 blocks

    prep_kernel<<<prepGrid, 256, 0, stream>>>(Wk, Wv, Wr, Wo, wkb, wvb, wrb, wob,
                                              cvtBlocks,
                                              x, mk, mv, mr, xmk, xmv, xmr,
                                              total);

    // v and r GEMMs first (they consume xmv/xmr, freeing the space kf reuses)
    gemm_bt2<<<gemm2Grid, 256, 0, stream>>>(xmv, xmr, wvb, wrb, vb, rb, M, D, D);
    gemm_bt<float><<<gemmGrid, 256, 0, stream>>>(xmk, wkb, kf, M, D, D);

    wkv_pass1<<<p12Grid, 256, 0, stream>>>(kf, vb, td, al, bl, el);
    wkv_combine<<<cmbGrid, 256, 0, stream>>>(al, bl, el, td);
    wkv_pass2<<<p12Grid, 256, 0, stream>>>(kf, vb, rb, td, tf, al, bl, el, xo);

    gemm_bt<float><<<gemmGrid, 256, 0, stream>>>(xo, wob, out, M, D, D);
}